// Round 13
// baseline (179.715 us; speedup 1.0000x reference)
//
#include <hip/hip_runtime.h>
#include <hip/hip_bf16.h>
#include <cstdint>
#include <cstddef>

typedef __bf16 bf16;
typedef __bf16 bf16x4 __attribute__((ext_vector_type(4)));
typedef __bf16 bf16x8 __attribute__((ext_vector_type(8)));
typedef float f32x4 __attribute__((ext_vector_type(4)));
typedef float f32x16 __attribute__((ext_vector_type(16)));

#define LOG2E 1.4426950408889634f
#define QSCALE (0.03125f * LOG2E)   // C^-0.5 * log2(e), folded into Q

#define GLD16(gp, lp)                                                              \
  __builtin_amdgcn_global_load_lds((__attribute__((address_space(1))) void*)(gp),  \
                                   (__attribute__((address_space(3))) void*)(lp),  \
                                   16, 0, 0)

// ---------------- fused prep: x->bf16 + W_qkv^T + W_out^T (one launch) ----------------
__global__ void k_prep(const float* __restrict__ x, const float* __restrict__ Wqkv,
                       const float* __restrict__ Wout, bf16* __restrict__ xb,
                       bf16* __restrict__ wqT, bf16* __restrict__ woT) {
  const int blk = blockIdx.x, tid = threadIdx.x;
  if (blk < 2048) {  // cvt x: 2048 blocks x 256 thr x 8 elems
    int i = (blk * 256 + tid) * 8;
    const float4* p = (const float4*)(x + i);
    float4 a = p[0], b = p[1];
    bf16x8 o;
    o[0] = (bf16)a.x; o[1] = (bf16)a.y; o[2] = (bf16)a.z; o[3] = (bf16)a.w;
    o[4] = (bf16)b.x; o[5] = (bf16)b.y; o[6] = (bf16)b.z; o[7] = (bf16)b.w;
    *(bf16x8*)(xb + i) = o;
    return;
  }
  // transposes: [R][C] fp32 -> [C][R] bf16, 32x32 tiles, 256 thr as (32,8)
  const float* in;
  bf16* out;
  int R = 1024, C, bx, by;
  if (blk < 2048 + 3072) {
    in = Wqkv; out = wqT; C = 3072;
    bx = (blk - 2048) % 96; by = (blk - 2048) / 96;
  } else {
    in = Wout; out = woT; C = 1024;
    bx = (blk - 5120) % 32; by = (blk - 5120) / 32;
  }
  __shared__ float t[32][33];
  const int tx = tid & 31, ty = tid >> 5;
  int c0 = bx * 32, r0 = by * 32;
#pragma unroll
  for (int i = 0; i < 4; i++)
    t[ty + i * 8][tx] = in[(size_t)(r0 + ty + i * 8) * C + c0 + tx];
  __syncthreads();
#pragma unroll
  for (int i = 0; i < 4; i++)
    out[(size_t)(c0 + ty + i * 8) * R + r0 + tx] = (bf16)t[tx][ty + i * 8];
}

// ---------------- QKV GEMM: C = A[4096,1024] @ Bt[3072,1024]^T ----------------
// BK=64, 2-barrier skeleton (measured), NOW with 32x32x16 MFMA: per wave-K-step the
// same 16 ds_read_b128 feed 16 MFMAs of 32KFLOP (was 32 of 16KFLOP) -- half the
// MFMA instructions, +15% matrix-pipe ceiling (2382 vs 2075 TF ubench), same LDS
// bytes. Wave tile 64x64 = 2x2 of 32x32; C/D layout: col=l31,
// row=(reg&3)+8*(reg>>2)+4h (flash-verified). LDS 32KB, 3 blocks/CU.
__global__ __launch_bounds__(256, 3) void k_gemm_qkv(
    const bf16* __restrict__ A, const bf16* __restrict__ Bt,
    const float* __restrict__ bias,
    bf16* __restrict__ qb, bf16* __restrict__ kb, bf16* __restrict__ vb) {
  __shared__ __align__(16) bf16 As[128 * 64];
  __shared__ __align__(16) bf16 Bs[128 * 64];
  const int tid = threadIdx.x;
  const int lane = tid & 63, w = tid >> 6;
  const int l31 = lane & 31, h = lane >> 5;
  const int wm = (w >> 1) * 64, wn = (w & 1) * 64;
  const int bm = blockIdx.y * 128, bn = blockIdx.x * 128;
  f32x16 acc[2][2] = {};

  for (int kt = 0; kt < 1024; kt += 64) {
    __syncthreads();
#pragma unroll
    for (int p = 0; p < 4; p++) {
      int idx = p * 256 + tid;          // 1024 slots = 128 rows x 8 16B-blocks
      int row = idx >> 3, bq = idx & 7;
      int gb = bq ^ (row & 7);
      GLD16(A + (size_t)(bm + row) * 1024 + kt + gb * 8, As + idx * 8);
      GLD16(Bt + (size_t)(bn + row) * 1024 + kt + gb * 8, Bs + idx * 8);
    }
    __syncthreads();

#pragma unroll
    for (int kk = 0; kk < 4; kk++) {    // K=16 per step
      bf16x8 af[2], bfr[2];
#pragma unroll
      for (int mi = 0; mi < 2; mi++) {
        int row = wm + mi * 32 + l31;
        int sb = (2 * kk + h) ^ (row & 7);
        af[mi] = *(const bf16x8*)(As + row * 64 + sb * 8);
      }
#pragma unroll
      for (int ni = 0; ni < 2; ni++) {
        int row = wn + ni * 32 + l31;
        int sb = (2 * kk + h) ^ (row & 7);
        bfr[ni] = *(const bf16x8*)(Bs + row * 64 + sb * 8);
      }
#pragma unroll
      for (int mi = 0; mi < 2; mi++)
#pragma unroll
        for (int ni = 0; ni < 2; ni++)
          acc[mi][ni] =
              __builtin_amdgcn_mfma_f32_32x32x16_bf16(af[mi], bfr[ni], acc[mi][ni], 0, 0, 0);
    }
  }

  // epilogue: C row = bm+wm+mi*32+(r&3)+8*(r>>2)+4h, col = bn+wn+ni*32+l31
#pragma unroll
  for (int ni = 0; ni < 2; ni++) {
    int col = bn + wn + ni * 32 + l31;
    float bv = bias[col];
    int which = col >> 10, cc = col & 1023;  // wave-uniform per ni-tile (32-aligned)
    int hh = cc >> 6, d = cc & 63;
    if (which == 2) {
#pragma unroll
      for (int mi = 0; mi < 2; mi++)
#pragma unroll
        for (int g = 0; g < 4; g++) {
          int rowb = bm + wm + mi * 32 + 8 * g + 4 * h;  // 4 consecutive rows r=g*4..g*4+3
          int b = rowb >> 11, n0 = rowb & 2047;
          // key-permuted V store: swap bits 2<->3 of n within each 16-key group,
          // so k_flash's PV fragment reads become single b128 blocks.
          int n0p = (n0 & ~12) | ((n0 & 4) << 1) | ((n0 & 8) >> 1);
          bf16x4 vv;
#pragma unroll
          for (int r = 0; r < 4; r++) vv[r] = (bf16)(acc[mi][ni][4 * g + r] + bv);
          *(bf16x4*)(vb + ((size_t)(b * 16 + hh) * 64 + d) * 2048 + n0p) = vv;
        }
    } else {
#pragma unroll
      for (int mi = 0; mi < 2; mi++)
#pragma unroll
        for (int r = 0; r < 16; r++) {
          int row = bm + wm + mi * 32 + (r & 3) + 8 * (r >> 2) + 4 * h;
          int b = row >> 11, n = row & 2047;
          float v = acc[mi][ni][r] + bv;
          if (which == 0)
            qb[((size_t)(b * 16 + hh) * 2048 + n) * 64 + d] = (bf16)(v * QSCALE);
          else
            kb[((size_t)(b * 16 + hh) * 2048 + n) * 64 + d] = (bf16)v;
        }
    }
  }
}

// ---------------- output GEMM: out = A[4096,1024] @ Bt[1024,1024]^T + bias ----------
// BK=64, 64x128 tiles, grid 512 = 2 blocks/CU, XCD-chunked; 32x32x16 MFMA
// (wave tile 32x64 = 1x2 of 32x32). LDS 24KB.
__global__ __launch_bounds__(256, 2) void k_gemm_out(
    const bf16* __restrict__ A, const bf16* __restrict__ Bt,
    const float* __restrict__ bias, float* __restrict__ outF) {
  __shared__ __align__(16) bf16 As[64 * 64];
  __shared__ __align__(16) bf16 Bs[128 * 64];
  const int tid = threadIdx.x;
  const int lane = tid & 63, w = tid >> 6;
  const int l31 = lane & 31, h = lane >> 5;
  const int wm = (w >> 1) * 32, wn = (w & 1) * 64;
  const int cid = (blockIdx.x & 7) * 64 + (blockIdx.x >> 3);
  const int bn = (cid & 7) * 128, bm = (cid >> 3) * 64;
  f32x16 acc[2] = {};

  for (int kt = 0; kt < 1024; kt += 64) {
    __syncthreads();
#pragma unroll
    for (int p = 0; p < 2; p++) {
      int idx = p * 256 + tid;  // As: 512 slots = 64 rows x 8 blocks
      int row = idx >> 3, bq = idx & 7;
      int gb = bq ^ (row & 7);
      GLD16(A + (size_t)(bm + row) * 1024 + kt + gb * 8, As + idx * 8);
    }
#pragma unroll
    for (int p = 0; p < 4; p++) {
      int idx = p * 256 + tid;  // Bs: 1024 slots = 128 rows x 8 blocks
      int row = idx >> 3, bq = idx & 7;
      int gb = bq ^ (row & 7);
      GLD16(Bt + (size_t)(bn + row) * 1024 + kt + gb * 8, Bs + idx * 8);
    }
    __syncthreads();

#pragma unroll
    for (int kk = 0; kk < 4; kk++) {
      int rowA = wm + l31;
      int sbA = (2 * kk + h) ^ (rowA & 7);
      bf16x8 af = *(const bf16x8*)(As + rowA * 64 + sbA * 8);
      bf16x8 bfr[2];
#pragma unroll
      for (int ni = 0; ni < 2; ni++) {
        int row = wn + ni * 32 + l31;
        int sb = (2 * kk + h) ^ (row & 7);
        bfr[ni] = *(const bf16x8*)(Bs + row * 64 + sb * 8);
      }
#pragma unroll
      for (int ni = 0; ni < 2; ni++)
        acc[ni] = __builtin_amdgcn_mfma_f32_32x32x16_bf16(af, bfr[ni], acc[ni], 0, 0, 0);
    }
  }

#pragma unroll
  for (int ni = 0; ni < 2; ni++) {
    int col = bn + wn + ni * 32 + l31;
    float bv = bias[col];
#pragma unroll
    for (int r = 0; r < 16; r++) {
      int row = bm + wm + (r & 3) + 8 * (r >> 2) + 4 * h;
      outF[(size_t)row * 1024 + col] = acc[ni][r] + bv;
    }
  }
}

// ---------------- flash attention (round-4 version, verbatim: measured 47.6-48.1us) --
// 4-wave blocks, grid 512 = 2 blocks/CU, dbuf K/V (32KB), one __syncthreads/iter.
// 8 variants (schedules, barriers, occupancy, read-amortization) all landed 47.3-53:
// this decomposition's fixed point. P trick: S^T=K*Q^T leaves lane with
// key=(reg&3)+8*(reg>>2)+4h, qrow=l&31; PV k-order arbitrary -> pf[c] = exp2 of own
// acc regs in order (no cross-lane, no LDS round-trip); V stored key-permuted
// (bits 2<->3, in k_gemm_qkv) so each pf[c]'s V A-fragment is one b128.
__global__ __launch_bounds__(256, 2) void k_flash(
    const bf16* __restrict__ Q, const bf16* __restrict__ K,
    const bf16* __restrict__ V, bf16* __restrict__ O) {
  __shared__ __align__(16) bf16 Kt[2][64 * 64];  // [key][d]
  __shared__ __align__(16) bf16 Vt[2][64 * 64];  // [d][key'] (key-permuted)
  const int tid = threadIdx.x;
  const int lane = tid & 63, w = tid >> 6;
  const int l31 = lane & 31, h = lane >> 5;
  const int x7 = l31 & 7;
  const int cid = ((blockIdx.x & 7) << 6) | (blockIdx.x >> 3);  // bijective XCD chunking
  const int qt = cid & 15, bh = cid >> 4;
  const bf16* qh = Q + (size_t)bh * 2048 * 64;
  const bf16* kh = K + (size_t)bh * 2048 * 64;
  const bf16* vh = V + (size_t)bh * 64 * 2048;
  const int qrow = qt * 128 + w * 32 + l31;

  // Q fragments (B-operand of S^T = K*Q^T): slot(h,j) -> d = 16c + 8h + j
  bf16x8 qf[4];
#pragma unroll
  for (int c4 = 0; c4 < 4; c4++)
    qf[c4] = *(const bf16x8*)(qh + (size_t)qrow * 64 + c4 * 16 + h * 8);

  bf16x8 ones;
#pragma unroll
  for (int j = 0; j < 8; j++) ones[j] = (bf16)1.0f;
  f32x16 z16 = {};  // loop-invariant zero C-operand for the first S-MFMA

  f32x16 o0 = {}, o1 = {};  // O^T acc: d = 32*db + (reg&3)+8*(reg>>2)+4h, col = qrow
  f32x16 lacc = {};         // ones-MFMA row-sum acc (all rows equal per col)

  auto stage = [&](int kt2, int buf) {
#pragma unroll
    for (int pp = 0; pp < 2; pp++) {
      int idx = pp * 256 + tid;
      int row = idx >> 3, bq = idx & 7, gb = bq ^ (row & 7);
      GLD16(kh + (size_t)(kt2 * 64 + row) * 64 + gb * 8, &Kt[buf][idx * 8]);
      GLD16(vh + (size_t)row * 2048 + kt2 * 64 + gb * 8, &Vt[buf][idx * 8]);
    }
  };

  stage(0, 0);

  for (int kt2 = 0; kt2 < 32; kt2++) {
    const int p = kt2 & 1;
    __syncthreads();               // publishes buf[p]; prior readers of buf[p^1] done
    if (kt2 < 31) stage(kt2 + 1, p ^ 1);
    const bf16* Kb = &Kt[p][0];
    const bf16* Vb = &Vt[p][0];

    // S^T = K*Q^T, two 32-key blocks
    f32x16 a0, a1;
    {
      const bf16* k0 = Kb + l31 * 64;
      const bf16* k1 = k0 + 32 * 64;
      __builtin_amdgcn_s_setprio(1);
#pragma unroll
      for (int c4 = 0; c4 < 4; c4++) {
        int off = ((2 * c4 + h) ^ x7) << 3;
        bf16x8 kf0 = *(const bf16x8*)(k0 + off);
        bf16x8 kf1 = *(const bf16x8*)(k1 + off);
        a0 = __builtin_amdgcn_mfma_f32_32x32x16_bf16(kf0, qf[c4], c4 ? a0 : z16, 0, 0, 0);
        a1 = __builtin_amdgcn_mfma_f32_32x32x16_bf16(kf1, qf[c4], c4 ? a1 : z16, 0, 0, 0);
      }
      __builtin_amdgcn_s_setprio(0);
    }

    const bf16* v0 = Vb + l31 * 64;
    const bf16* v1 = v0 + 32 * 64;

    // half 1: P(c=0,1) from a0, then PV + lsum MFMAs
    {
      bf16x8 pf0, pf1;
#pragma unroll
      for (int j = 0; j < 8; j++) {
        pf0[j] = (bf16)__builtin_amdgcn_exp2f(a0[j]);
        pf1[j] = (bf16)__builtin_amdgcn_exp2f(a0[8 + j]);
      }
      int e0 = ((0 + h) ^ x7) << 3, e1 = ((2 + h) ^ x7) << 3;
      bf16x8 vf00 = *(const bf16x8*)(v0 + e0);
      bf16x8 vf10 = *(const bf16x8*)(v1 + e0);
      bf16x8 vf01 = *(const bf16x8*)(v0 + e1);
      bf16x8 vf11 = *(const bf16x8*)(v1 + e1);
      __builtin_amdgcn_s_setprio(1);
      lacc = __builtin_amdgcn_mfma_f32_32x32x16_bf16(ones, pf0, lacc, 0, 0, 0);
      o0 = __builtin_amdgcn_mfma_f32_32x32x16_bf16(vf00, pf0, o0, 0, 0, 0);
      o1 = __builtin_amdgcn_mfma_f32_32x32x16_bf16(vf10, pf0, o1, 0, 0, 0);
      lacc = __builtin_amdgcn_mfma_f32_32x32x16_bf16(ones, pf1, lacc, 0, 0, 0);
      o0 = __builtin_amdgcn_mfma_f32_32x32x16_bf16(vf01, pf1, o0, 0, 0, 0);
      o1 = __builtin_amdgcn_mfma_f32_32x32x16_bf16(vf11, pf1, o1, 0, 0, 0);
      __builtin_amdgcn_s_setprio(0);
    }

    // half 2: P(c=2,3) from a1, then PV + lsum MFMAs
    {
      bf16x8 pf2, pf3;
#pragma unroll
      for (int j = 0; j < 8; j++) {
        pf2[j] = (bf16)__builtin_amdgcn_exp2f(a1[j]);
        pf3[j] = (bf16)__builtin_amdgcn_exp2f(a1[8 + j]);
      }
      int e2 = ((4 + h) ^ x7) << 3, e3 = ((6 + h) ^ x7) << 3;
      bf16x8 vf02 = *(const bf16x8*)(v0 + e2);
      bf16x8 vf12 = *(const bf16x8*)(v1 + e2);
      bf16x8 vf03 = *(const bf16x8*)(v0 + e3);
      bf16x8 vf13 = *(const bf16x8*)(v1 + e3);
      __builtin_amdgcn_s_setprio(1);
      lacc = __builtin_amdgcn_mfma_f32_32x32x16_bf16(ones, pf2, lacc, 0, 0, 0);
      o0 = __builtin_amdgcn_mfma_f32_32x32x16_bf16(vf02, pf2, o0, 0, 0, 0);
      o1 = __builtin_amdgcn_mfma_f32_32x32x16_bf16(vf12, pf2, o1, 0, 0, 0);
      lacc = __builtin_amdgcn_mfma_f32_32x32x16_bf16(ones, pf3, lacc, 0, 0, 0);
      o0 = __builtin_amdgcn_mfma_f32_32x32x16_bf16(vf03, pf3, o0, 0, 0, 0);
      o1 = __builtin_amdgcn_mfma_f32_32x32x16_bf16(vf13, pf3, o1, 0, 0, 0);
      __builtin_amdgcn_s_setprio(0);
    }
  }

  // epilogue: lacc rows all hold the full key-sum for col = qrow (both halves)
  float inv = 1.0f / lacc[0];
  const int bb = bh >> 4, hh = bh & 15;
  bf16* orow = O + ((size_t)bb * 2048 + qrow) * 1024 + hh * 64;
#pragma unroll
  for (int g = 0; g < 4; g++) {
    bf16x4 ov0, ov1;
#pragma unroll
    for (int r = 0; r < 4; r++) {
      ov0[r] = (bf16)(o0[4 * g + r] * inv);
      ov1[r] = (bf16)(o1[4 * g + r] * inv);
    }
    *(bf16x4*)(orow + 8 * g + 4 * h) = ov0;        // d = 8g + 4h + r
    *(bf16x4*)(orow + 32 + 8 * g + 4 * h) = ov1;   // d = 32 + 8g + 4h + r
  }
}

// ---------------- launch ----------------

extern "C" void kernel_launch(void* const* d_in, const int* in_sizes, int n_in,
                              void* d_out, int out_size, void* d_ws, size_t ws_size,
                              hipStream_t stream) {
  (void)in_sizes; (void)n_in; (void)out_size; (void)ws_size;
  const float* x    = (const float*)d_in[0];
  const float* Wqkv = (const float*)d_in[1];
  const float* bqkv = (const float*)d_in[2];
  const float* Wout = (const float*)d_in[3];
  const float* bout = (const float*)d_in[4];
  float* out = (float*)d_out;

  char* ws = (char*)d_ws;
  size_t off = 0;
  auto take = [&](size_t bytes) {
    char* p = ws + off;
    off += (bytes + 255) & ~(size_t)255;
    return p;
  };
  bf16* xb   = (bf16*)take((size_t)4096 * 1024 * 2);
  bf16* wqT  = (bf16*)take((size_t)3072 * 1024 * 2);
  bf16* woT  = (bf16*)take((size_t)1024 * 1024 * 2);
  bf16* qbuf = (bf16*)take((size_t)32 * 2048 * 64 * 2);
  bf16* kbuf = (bf16*)take((size_t)32 * 2048 * 64 * 2);
  bf16* vbuf = (bf16*)take((size_t)32 * 2048 * 64 * 2);
  bf16* aout = (bf16*)take((size_t)4096 * 1024 * 2);

  k_prep<<<6144, 256, 0, stream>>>(x, Wqkv, Wout, xb, wqT, woT);
  k_gemm_qkv<<<dim3(24, 32), 256, 0, stream>>>(xb, wqT, bqkv, qbuf, kbuf, vbuf);
  k_flash<<<dim3(512), 256, 0, stream>>>(qbuf, kbuf, vbuf, aout);
  k_gemm_out<<<dim3(512), 256, 0, stream>>>(aout, woT, bout, out);
}

// Round 14
// 178.078 us; speedup vs baseline: 1.0092x; 1.0092x over previous
//
#include <hip/hip_runtime.h>
#include <hip/hip_bf16.h>
#include <cstdint>
#include <cstddef>

typedef __bf16 bf16;
typedef __bf16 bf16x4 __attribute__((ext_vector_type(4)));
typedef __bf16 bf16x8 __attribute__((ext_vector_type(8)));
typedef float f32x4 __attribute__((ext_vector_type(4)));
typedef float f32x16 __attribute__((ext_vector_type(16)));

#define LOG2E 1.4426950408889634f
#define QSCALE (0.03125f * LOG2E)   // C^-0.5 * log2(e), folded into Q

#define GLD16(gp, lp)                                                              \
  __builtin_amdgcn_global_load_lds((__attribute__((address_space(1))) void*)(gp),  \
                                   (__attribute__((address_space(3))) void*)(lp),  \
                                   16, 0, 0)

// ---------------- fused prep: x->bf16 + W_qkv^T + W_out^T (one launch) ----------------
__global__ void k_prep(const float* __restrict__ x, const float* __restrict__ Wqkv,
                       const float* __restrict__ Wout, bf16* __restrict__ xb,
                       bf16* __restrict__ wqT, bf16* __restrict__ woT) {
  const int blk = blockIdx.x, tid = threadIdx.x;
  if (blk < 2048) {  // cvt x: 2048 blocks x 256 thr x 8 elems
    int i = (blk * 256 + tid) * 8;
    const float4* p = (const float4*)(x + i);
    float4 a = p[0], b = p[1];
    bf16x8 o;
    o[0] = (bf16)a.x; o[1] = (bf16)a.y; o[2] = (bf16)a.z; o[3] = (bf16)a.w;
    o[4] = (bf16)b.x; o[5] = (bf16)b.y; o[6] = (bf16)b.z; o[7] = (bf16)b.w;
    *(bf16x8*)(xb + i) = o;
    return;
  }
  // transposes: [R][C] fp32 -> [C][R] bf16, 32x32 tiles, 256 thr as (32,8)
  const float* in;
  bf16* out;
  int R = 1024, C, bx, by;
  if (blk < 2048 + 3072) {
    in = Wqkv; out = wqT; C = 3072;
    bx = (blk - 2048) % 96; by = (blk - 2048) / 96;
  } else {
    in = Wout; out = woT; C = 1024;
    bx = (blk - 5120) % 32; by = (blk - 5120) / 32;
  }
  __shared__ float t[32][33];
  const int tx = tid & 31, ty = tid >> 5;
  int c0 = bx * 32, r0 = by * 32;
#pragma unroll
  for (int i = 0; i < 4; i++)
    t[ty + i * 8][tx] = in[(size_t)(r0 + ty + i * 8) * C + c0 + tx];
  __syncthreads();
#pragma unroll
  for (int i = 0; i < 4; i++)
    out[(size_t)(c0 + ty + i * 8) * R + r0 + tx] = (bf16)t[tx][ty + i * 8];
}

// ---------------- QKV GEMM: C = A[4096,1024] @ Bt[3072,1024]^T ----------------
// Round-12 measured structure (BK=64, 2-barrier, 16x16 MFMA 4x4 acc, XOR swizzle)
// + NEW: bijective XCD chunking (768 = 8 x 96): each XCD owns 4 M-rows x all N,
// making its 1MB A-slice L2-resident (was scattered across 8 XCDs).
__global__ __launch_bounds__(256, 3) void k_gemm_qkv(
    const bf16* __restrict__ A, const bf16* __restrict__ Bt,
    const float* __restrict__ bias,
    bf16* __restrict__ qb, bf16* __restrict__ kb, bf16* __restrict__ vb) {
  __shared__ __align__(16) bf16 As[128 * 64];
  __shared__ __align__(16) bf16 Bs[128 * 64];
  const int tid = threadIdx.x;
  const int lane = tid & 63, w = tid >> 6;
  const int quad = lane >> 4, l16 = lane & 15;
  const int wm = (w >> 1) * 64, wn = (w & 1) * 64;
  const int lin = blockIdx.y * 24 + blockIdx.x;
  const int cid = (lin & 7) * 96 + (lin >> 3);   // bijective XCD chunking
  const int bm = (cid / 24) * 128, bn = (cid % 24) * 128;
  f32x4 acc[4][4] = {};

  for (int kt = 0; kt < 1024; kt += 64) {
    __syncthreads();
#pragma unroll
    for (int p = 0; p < 4; p++) {
      int idx = p * 256 + tid;          // 1024 slots = 128 rows x 8 16B-blocks
      int row = idx >> 3, bq = idx & 7;
      int gb = bq ^ (row & 7);
      GLD16(A + (size_t)(bm + row) * 1024 + kt + gb * 8, As + idx * 8);
      GLD16(Bt + (size_t)(bn + row) * 1024 + kt + gb * 8, Bs + idx * 8);
    }
    __syncthreads();

#pragma unroll
    for (int kk = 0; kk < 2; kk++) {
      bf16x8 af[4], bfr[4];
#pragma unroll
      for (int mi = 0; mi < 4; mi++) {
        int row = wm + mi * 16 + l16;
        int sb = (kk * 4 + quad) ^ (row & 7);
        af[mi] = *(const bf16x8*)(As + row * 64 + sb * 8);
      }
#pragma unroll
      for (int ni = 0; ni < 4; ni++) {
        int row = wn + ni * 16 + l16;
        int sb = (kk * 4 + quad) ^ (row & 7);
        bfr[ni] = *(const bf16x8*)(Bs + row * 64 + sb * 8);
      }
#pragma unroll
      for (int mi = 0; mi < 4; mi++)
#pragma unroll
        for (int ni = 0; ni < 4; ni++)
          acc[mi][ni] =
              __builtin_amdgcn_mfma_f32_16x16x32_bf16(af[mi], bfr[ni], acc[mi][ni], 0, 0, 0);
    }
  }

#pragma unroll
  for (int ni = 0; ni < 4; ni++) {
    int col = bn + wn + ni * 16 + l16;
    float bv = bias[col];
    int which = col >> 10, cc = col & 1023;  // wave-uniform per ni-tile
    int h = cc >> 6, d = cc & 63;
    if (which == 2) {
#pragma unroll
      for (int mi = 0; mi < 4; mi++) {
        int rowb = bm + wm + mi * 16 + quad * 4;
        int b = rowb >> 11, n0 = rowb & 2047;
        // key-permuted V store: swap bits 2<->3 of n within each 16-key group,
        // so k_flash's PV fragment {block g, half h; block g+1, half h} becomes
        // one contiguous 16B LDS block (read with ds_read_b128, K-like pattern).
        int n0p = (n0 & ~12) | ((n0 & 4) << 1) | ((n0 & 8) >> 1);
        bf16x4 vv;
#pragma unroll
        for (int r = 0; r < 4; r++) vv[r] = (bf16)(acc[mi][ni][r] + bv);
        *(bf16x4*)(vb + ((size_t)(b * 16 + h) * 64 + d) * 2048 + n0p) = vv;
      }
    } else {
#pragma unroll
      for (int mi = 0; mi < 4; mi++)
#pragma unroll
        for (int r = 0; r < 4; r++) {
          int row = bm + wm + mi * 16 + quad * 4 + r;
          int b = row >> 11, n = row & 2047;
          float v = acc[mi][ni][r] + bv;
          if (which == 0)
            qb[((size_t)(b * 16 + h) * 2048 + n) * 64 + d] = (bf16)(v * QSCALE);
          else
            kb[((size_t)(b * 16 + h) * 2048 + n) * 64 + d] = (bf16)v;
        }
    }
  }
}

// ---------------- output GEMM: out = A[4096,1024] @ Bt[1024,1024]^T + bias ----------
// (round-12 measured version.) BK=64, 64x128 tiles, grid 512 = 2 blocks/CU,
// XCD-chunked, 16x16 MFMA. LDS 24KB.
__global__ __launch_bounds__(256, 2) void k_gemm_out(
    const bf16* __restrict__ A, const bf16* __restrict__ Bt,
    const float* __restrict__ bias, float* __restrict__ outF) {
  __shared__ __align__(16) bf16 As[64 * 64];
  __shared__ __align__(16) bf16 Bs[128 * 64];
  const int tid = threadIdx.x;
  const int lane = tid & 63, w = tid >> 6;
  const int quad = lane >> 4, l16 = lane & 15;
  const int wm = (w >> 1) * 32, wn = (w & 1) * 64;
  const int cid = (blockIdx.x & 7) * 64 + (blockIdx.x >> 3);
  const int bn = (cid & 7) * 128, bm = (cid >> 3) * 64;
  f32x4 acc[2][4] = {};

  for (int kt = 0; kt < 1024; kt += 64) {
    __syncthreads();
#pragma unroll
    for (int p = 0; p < 2; p++) {
      int idx = p * 256 + tid;  // As: 512 slots = 64 rows x 8 blocks
      int row = idx >> 3, bq = idx & 7;
      int gb = bq ^ (row & 7);
      GLD16(A + (size_t)(bm + row) * 1024 + kt + gb * 8, As + idx * 8);
    }
#pragma unroll
    for (int p = 0; p < 4; p++) {
      int idx = p * 256 + tid;  // Bs: 1024 slots = 128 rows x 8 blocks
      int row = idx >> 3, bq = idx & 7;
      int gb = bq ^ (row & 7);
      GLD16(Bt + (size_t)(bn + row) * 1024 + kt + gb * 8, Bs + idx * 8);
    }
    __syncthreads();

#pragma unroll
    for (int kk = 0; kk < 2; kk++) {
      bf16x8 af[2], bfr[4];
#pragma unroll
      for (int mi = 0; mi < 2; mi++) {
        int row = wm + mi * 16 + l16;
        int sb = (kk * 4 + quad) ^ (row & 7);
        af[mi] = *(const bf16x8*)(As + row * 64 + sb * 8);
      }
#pragma unroll
      for (int ni = 0; ni < 4; ni++) {
        int row = wn + ni * 16 + l16;
        int sb = (kk * 4 + quad) ^ (row & 7);
        bfr[ni] = *(const bf16x8*)(Bs + row * 64 + sb * 8);
      }
#pragma unroll
      for (int mi = 0; mi < 2; mi++)
#pragma unroll
        for (int ni = 0; ni < 4; ni++)
          acc[mi][ni] =
              __builtin_amdgcn_mfma_f32_16x16x32_bf16(af[mi], bfr[ni], acc[mi][ni], 0, 0, 0);
    }
  }

#pragma unroll
  for (int ni = 0; ni < 4; ni++) {
    int col = bn + wn + ni * 16 + l16;
    float bv = bias[col];
#pragma unroll
    for (int mi = 0; mi < 2; mi++)
#pragma unroll
      for (int r = 0; r < 4; r++) {
        int row = bm + wm + mi * 16 + quad * 4 + r;
        outF[(size_t)row * 1024 + col] = acc[mi][ni][r] + bv;
      }
  }
}

// ---------------- flash attention (round-4 version, verbatim: measured 47.6-48.1us) --
// 4-wave blocks, grid 512 = 2 blocks/CU, dbuf K/V (32KB), one __syncthreads/iter.
// 8 variants (schedules, barriers, occupancy, read-amortization) all landed 47.3-53:
// this decomposition's fixed point. P trick: S^T=K*Q^T leaves lane with
// key=(reg&3)+8*(reg>>2)+4h, qrow=l&31; PV k-order arbitrary -> pf[c] = exp2 of own
// acc regs in order (no cross-lane, no LDS round-trip); V stored key-permuted
// (bits 2<->3, in k_gemm_qkv) so each pf[c]'s V A-fragment is one b128.
__global__ __launch_bounds__(256, 2) void k_flash(
    const bf16* __restrict__ Q, const bf16* __restrict__ K,
    const bf16* __restrict__ V, bf16* __restrict__ O) {
  __shared__ __align__(16) bf16 Kt[2][64 * 64];  // [key][d]
  __shared__ __align__(16) bf16 Vt[2][64 * 64];  // [d][key'] (key-permuted)
  const int tid = threadIdx.x;
  const int lane = tid & 63, w = tid >> 6;
  const int l31 = lane & 31, h = lane >> 5;
  const int x7 = l31 & 7;
  const int cid = ((blockIdx.x & 7) << 6) | (blockIdx.x >> 3);  // bijective XCD chunking
  const int qt = cid & 15, bh = cid >> 4;
  const bf16* qh = Q + (size_t)bh * 2048 * 64;
  const bf16* kh = K + (size_t)bh * 2048 * 64;
  const bf16* vh = V + (size_t)bh * 64 * 2048;
  const int qrow = qt * 128 + w * 32 + l31;

  // Q fragments (B-operand of S^T = K*Q^T): slot(h,j) -> d = 16c + 8h + j
  bf16x8 qf[4];
#pragma unroll
  for (int c4 = 0; c4 < 4; c4++)
    qf[c4] = *(const bf16x8*)(qh + (size_t)qrow * 64 + c4 * 16 + h * 8);

  bf16x8 ones;
#pragma unroll
  for (int j = 0; j < 8; j++) ones[j] = (bf16)1.0f;
  f32x16 z16 = {};  // loop-invariant zero C-operand for the first S-MFMA

  f32x16 o0 = {}, o1 = {};  // O^T acc: d = 32*db + (reg&3)+8*(reg>>2)+4h, col = qrow
  f32x16 lacc = {};         // ones-MFMA row-sum acc (all rows equal per col)

  auto stage = [&](int kt2, int buf) {
#pragma unroll
    for (int pp = 0; pp < 2; pp++) {
      int idx = pp * 256 + tid;
      int row = idx >> 3, bq = idx & 7, gb = bq ^ (row & 7);
      GLD16(kh + (size_t)(kt2 * 64 + row) * 64 + gb * 8, &Kt[buf][idx * 8]);
      GLD16(vh + (size_t)row * 2048 + kt2 * 64 + gb * 8, &Vt[buf][idx * 8]);
    }
  };

  stage(0, 0);

  for (int kt2 = 0; kt2 < 32; kt2++) {
    const int p = kt2 & 1;
    __syncthreads();               // publishes buf[p]; prior readers of buf[p^1] done
    if (kt2 < 31) stage(kt2 + 1, p ^ 1);
    const bf16* Kb = &Kt[p][0];
    const bf16* Vb = &Vt[p][0];

    // S^T = K*Q^T, two 32-key blocks
    f32x16 a0, a1;
    {
      const bf16* k0 = Kb + l31 * 64;
      const bf16* k1 = k0 + 32 * 64;
      __builtin_amdgcn_s_setprio(1);
#pragma unroll
      for (int c4 = 0; c4 < 4; c4++) {
        int off = ((2 * c4 + h) ^ x7) << 3;
        bf16x8 kf0 = *(const bf16x8*)(k0 + off);
        bf16x8 kf1 = *(const bf16x8*)(k1 + off);
        a0 = __builtin_amdgcn_mfma_f32_32x32x16_bf16(kf0, qf[c4], c4 ? a0 : z16, 0, 0, 0);
        a1 = __builtin_amdgcn_mfma_f32_32x32x16_bf16(kf1, qf[c4], c4 ? a1 : z16, 0, 0, 0);
      }
      __builtin_amdgcn_s_setprio(0);
    }

    const bf16* v0 = Vb + l31 * 64;
    const bf16* v1 = v0 + 32 * 64;

    // half 1: P(c=0,1) from a0, then PV + lsum MFMAs
    {
      bf16x8 pf0, pf1;
#pragma unroll
      for (int j = 0; j < 8; j++) {
        pf0[j] = (bf16)__builtin_amdgcn_exp2f(a0[j]);
        pf1[j] = (bf16)__builtin_amdgcn_exp2f(a0[8 + j]);
      }
      int e0 = ((0 + h) ^ x7) << 3, e1 = ((2 + h) ^ x7) << 3;
      bf16x8 vf00 = *(const bf16x8*)(v0 + e0);
      bf16x8 vf10 = *(const bf16x8*)(v1 + e0);
      bf16x8 vf01 = *(const bf16x8*)(v0 + e1);
      bf16x8 vf11 = *(const bf16x8*)(v1 + e1);
      __builtin_amdgcn_s_setprio(1);
      lacc = __builtin_amdgcn_mfma_f32_32x32x16_bf16(ones, pf0, lacc, 0, 0, 0);
      o0 = __builtin_amdgcn_mfma_f32_32x32x16_bf16(vf00, pf0, o0, 0, 0, 0);
      o1 = __builtin_amdgcn_mfma_f32_32x32x16_bf16(vf10, pf0, o1, 0, 0, 0);
      lacc = __builtin_amdgcn_mfma_f32_32x32x16_bf16(ones, pf1, lacc, 0, 0, 0);
      o0 = __builtin_amdgcn_mfma_f32_32x32x16_bf16(vf01, pf1, o0, 0, 0, 0);
      o1 = __builtin_amdgcn_mfma_f32_32x32x16_bf16(vf11, pf1, o1, 0, 0, 0);
      __builtin_amdgcn_s_setprio(0);
    }

    // half 2: P(c=2,3) from a1, then PV + lsum MFMAs
    {
      bf16x8 pf2, pf3;
#pragma unroll
      for (int j = 0; j < 8; j++) {
        pf2[j] = (bf16)__builtin_amdgcn_exp2f(a1[j]);
        pf3[j] = (bf16)__builtin_amdgcn_exp2f(a1[8 + j]);
      }
      int e2 = ((4 + h) ^ x7) << 3, e3 = ((6 + h) ^ x7) << 3;
      bf16x8 vf02 = *(const bf16x8*)(v0 + e2);
      bf16x8 vf12 = *(const bf16x8*)(v1 + e2);
      bf16x8 vf03 = *(const bf16x8*)(v0 + e3);
      bf16x8 vf13 = *(const bf16x8*)(v1 + e3);
      __builtin_amdgcn_s_setprio(1);
      lacc = __builtin_amdgcn_mfma_f32_32x32x16_bf16(ones, pf2, lacc, 0, 0, 0);
      o0 = __builtin_amdgcn_mfma_f32_32x32x16_bf16(vf02, pf2, o0, 0, 0, 0);
      o1 = __builtin_amdgcn_mfma_f32_32x32x16_bf16(vf12, pf2, o1, 0, 0, 0);
      lacc = __builtin_amdgcn_mfma_f32_32x32x16_bf16(ones, pf3, lacc, 0, 0, 0);
      o0 = __builtin_amdgcn_mfma_f32_32x32x16_bf16(vf03, pf3, o0, 0, 0, 0);
      o1 = __builtin_amdgcn_mfma_f32_32x32x16_bf16(vf13, pf3, o1, 0, 0, 0);
      __builtin_amdgcn_s_setprio(0);
    }
  }

  // epilogue: lacc rows all hold the full key-sum for col = qrow (both halves)
  float inv = 1.0f / lacc[0];
  const int bb = bh >> 4, hh = bh & 15;
  bf16* orow = O + ((size_t)bb * 2048 + qrow) * 1024 + hh * 64;
#pragma unroll
  for (int g = 0; g < 4; g++) {
    bf16x4 ov0, ov1;
#pragma unroll
    for (int r = 0; r < 4; r++) {
      ov0[r] = (bf16)(o0[4 * g + r] * inv);
      ov1[r] = (bf16)(o1[4 * g + r] * inv);
    }
    *(bf16x4*)(orow + 8 * g + 4 * h) = ov0;        // d = 8g + 4h + r
    *(bf16x4*)(orow + 32 + 8 * g + 4 * h) = ov1;   // d = 32 + 8g + 4h + r
  }
}

// ---------------- launch ----------------

extern "C" void kernel_launch(void* const* d_in, const int* in_sizes, int n_in,
                              void* d_out, int out_size, void* d_ws, size_t ws_size,
                              hipStream_t stream) {
  (void)in_sizes; (void)n_in; (void)out_size; (void)ws_size;
  const float* x    = (const float*)d_in[0];
  const float* Wqkv = (const float*)d_in[1];
  const float* bqkv = (const float*)d_in[2];
  const float* Wout = (const float*)d_in[3];
  const float* bout = (const float*)d_in[4];
  float* out = (float*)d_out;

  char* ws = (char*)d_ws;
  size_t off = 0;
  auto take = [&](size_t bytes) {
    char* p = ws + off;
    off += (bytes + 255) & ~(size_t)255;
    return p;
  };
  bf16* xb   = (bf16*)take((size_t)4096 * 1024 * 2);
  bf16* wqT  = (bf16*)take((size_t)3072 * 1024 * 2);
  bf16* woT  = (bf16*)take((size_t)1024 * 1024 * 2);
  bf16* qbuf = (bf16*)take((size_t)32 * 2048 * 64 * 2);
  bf16* kbuf = (bf16*)take((size_t)32 * 2048 * 64 * 2);
  bf16* vbuf = (bf16*)take((size_t)32 * 2048 * 64 * 2);
  bf16* aout = (bf16*)take((size_t)4096 * 1024 * 2);

  k_prep<<<6144, 256, 0, stream>>>(x, Wqkv, Wout, xb, wqT, woT);
  k_gemm_qkv<<<dim3(24, 32), 256, 0, stream>>>(xb, wqT, bqkv, qbuf, kbuf, vbuf);
  k_flash<<<dim3(512), 256, 0, stream>>>(qbuf, kbuf, vbuf, aout);
  k_gemm_out<<<dim3(512), 256, 0, stream>>>(aout, woT, bout, out);
}

// Round 15
// 174.570 us; speedup vs baseline: 1.0295x; 1.0201x over previous
//
#include <hip/hip_runtime.h>
#include <hip/hip_bf16.h>
#include <cstdint>
#include <cstddef>

typedef __bf16 bf16;
typedef __bf16 bf16x4 __attribute__((ext_vector_type(4)));
typedef __bf16 bf16x8 __attribute__((ext_vector_type(8)));
typedef float f32x4 __attribute__((ext_vector_type(4)));
typedef float f32x16 __attribute__((ext_vector_type(16)));

#define LOG2E 1.4426950408889634f
#define QSCALE (0.03125f * LOG2E)   // C^-0.5 * log2(e), folded into Q

#define GLD16(gp, lp)                                                              \
  __builtin_amdgcn_global_load_lds((__attribute__((address_space(1))) void*)(gp),  \
                                   (__attribute__((address_space(3))) void*)(lp),  \
                                   16, 0, 0)

// ---------------- fused prep: x->bf16 + W_qkv^T + W_out^T (one launch) ----------------
__global__ void k_prep(const float* __restrict__ x, const float* __restrict__ Wqkv,
                       const float* __restrict__ Wout, bf16* __restrict__ xb,
                       bf16* __restrict__ wqT, bf16* __restrict__ woT) {
  const int blk = blockIdx.x, tid = threadIdx.x;
  if (blk < 2048) {  // cvt x: 2048 blocks x 256 thr x 8 elems
    int i = (blk * 256 + tid) * 8;
    const float4* p = (const float4*)(x + i);
    float4 a = p[0], b = p[1];
    bf16x8 o;
    o[0] = (bf16)a.x; o[1] = (bf16)a.y; o[2] = (bf16)a.z; o[3] = (bf16)a.w;
    o[4] = (bf16)b.x; o[5] = (bf16)b.y; o[6] = (bf16)b.z; o[7] = (bf16)b.w;
    *(bf16x8*)(xb + i) = o;
    return;
  }
  // transposes: [R][C] fp32 -> [C][R] bf16, 32x32 tiles, 256 thr as (32,8)
  const float* in;
  bf16* out;
  int R = 1024, C, bx, by;
  if (blk < 2048 + 3072) {
    in = Wqkv; out = wqT; C = 3072;
    bx = (blk - 2048) % 96; by = (blk - 2048) / 96;
  } else {
    in = Wout; out = woT; C = 1024;
    bx = (blk - 5120) % 32; by = (blk - 5120) / 32;
  }
  __shared__ float t[32][33];
  const int tx = tid & 31, ty = tid >> 5;
  int c0 = bx * 32, r0 = by * 32;
#pragma unroll
  for (int i = 0; i < 4; i++)
    t[ty + i * 8][tx] = in[(size_t)(r0 + ty + i * 8) * C + c0 + tx];
  __syncthreads();
#pragma unroll
  for (int i = 0; i < 4; i++)
    out[(size_t)(c0 + ty + i * 8) * R + r0 + tx] = (bf16)t[tx][ty + i * 8];
}

// ---------------- QKV GEMM: C = A[4096,1024] @ Bt[3072,1024]^T ----------------
// CHAMPION (round-12, 175.1us total): BK=64, 2-barrier skeleton, 16x16 MFMA 4x4 acc,
// XOR(row&7) block swizzle, default dispatch (XCD remap measured -3us -- omitted).
// 32x32 MFMA conversion measured -4.6us (ILP loss) -- omitted. LDS 32KB, 3 blocks/CU.
__global__ __launch_bounds__(256, 3) void k_gemm_qkv(
    const bf16* __restrict__ A, const bf16* __restrict__ Bt,
    const float* __restrict__ bias,
    bf16* __restrict__ qb, bf16* __restrict__ kb, bf16* __restrict__ vb) {
  __shared__ __align__(16) bf16 As[128 * 64];
  __shared__ __align__(16) bf16 Bs[128 * 64];
  const int tid = threadIdx.x;
  const int lane = tid & 63, w = tid >> 6;
  const int quad = lane >> 4, l16 = lane & 15;
  const int wm = (w >> 1) * 64, wn = (w & 1) * 64;
  const int bm = blockIdx.y * 128, bn = blockIdx.x * 128;
  f32x4 acc[4][4] = {};

  for (int kt = 0; kt < 1024; kt += 64) {
    __syncthreads();
#pragma unroll
    for (int p = 0; p < 4; p++) {
      int idx = p * 256 + tid;          // 1024 slots = 128 rows x 8 16B-blocks
      int row = idx >> 3, bq = idx & 7;
      int gb = bq ^ (row & 7);
      GLD16(A + (size_t)(bm + row) * 1024 + kt + gb * 8, As + idx * 8);
      GLD16(Bt + (size_t)(bn + row) * 1024 + kt + gb * 8, Bs + idx * 8);
    }
    __syncthreads();

#pragma unroll
    for (int kk = 0; kk < 2; kk++) {
      bf16x8 af[4], bfr[4];
#pragma unroll
      for (int mi = 0; mi < 4; mi++) {
        int row = wm + mi * 16 + l16;
        int sb = (kk * 4 + quad) ^ (row & 7);
        af[mi] = *(const bf16x8*)(As + row * 64 + sb * 8);
      }
#pragma unroll
      for (int ni = 0; ni < 4; ni++) {
        int row = wn + ni * 16 + l16;
        int sb = (kk * 4 + quad) ^ (row & 7);
        bfr[ni] = *(const bf16x8*)(Bs + row * 64 + sb * 8);
      }
#pragma unroll
      for (int mi = 0; mi < 4; mi++)
#pragma unroll
        for (int ni = 0; ni < 4; ni++)
          acc[mi][ni] =
              __builtin_amdgcn_mfma_f32_16x16x32_bf16(af[mi], bfr[ni], acc[mi][ni], 0, 0, 0);
    }
  }

#pragma unroll
  for (int ni = 0; ni < 4; ni++) {
    int col = bn + wn + ni * 16 + l16;
    float bv = bias[col];
    int which = col >> 10, cc = col & 1023;  // wave-uniform per ni-tile
    int h = cc >> 6, d = cc & 63;
    if (which == 2) {
#pragma unroll
      for (int mi = 0; mi < 4; mi++) {
        int rowb = bm + wm + mi * 16 + quad * 4;
        int b = rowb >> 11, n0 = rowb & 2047;
        // key-permuted V store: swap bits 2<->3 of n within each 16-key group,
        // so k_flash's PV fragment {block g, half h; block g+1, half h} becomes
        // one contiguous 16B LDS block (read with ds_read_b128, K-like pattern).
        int n0p = (n0 & ~12) | ((n0 & 4) << 1) | ((n0 & 8) >> 1);
        bf16x4 vv;
#pragma unroll
        for (int r = 0; r < 4; r++) vv[r] = (bf16)(acc[mi][ni][r] + bv);
        *(bf16x4*)(vb + ((size_t)(b * 16 + h) * 64 + d) * 2048 + n0p) = vv;
      }
    } else {
#pragma unroll
      for (int mi = 0; mi < 4; mi++)
#pragma unroll
        for (int r = 0; r < 4; r++) {
          int row = bm + wm + mi * 16 + quad * 4 + r;
          int b = row >> 11, n = row & 2047;
          float v = acc[mi][ni][r] + bv;
          if (which == 0)
            qb[((size_t)(b * 16 + h) * 2048 + n) * 64 + d] = (bf16)(v * QSCALE);
          else
            kb[((size_t)(b * 16 + h) * 2048 + n) * 64 + d] = (bf16)v;
        }
    }
  }
}

// ---------------- output GEMM: out = A[4096,1024] @ Bt[1024,1024]^T + bias ----------
// CHAMPION (round-12): BK=64, 64x128 tiles, grid 512 = 2 blocks/CU, XCD-chunked,
// 16x16 MFMA. LDS 24KB.
__global__ __launch_bounds__(256, 2) void k_gemm_out(
    const bf16* __restrict__ A, const bf16* __restrict__ Bt,
    const float* __restrict__ bias, float* __restrict__ outF) {
  __shared__ __align__(16) bf16 As[64 * 64];
  __shared__ __align__(16) bf16 Bs[128 * 64];
  const int tid = threadIdx.x;
  const int lane = tid & 63, w = tid >> 6;
  const int quad = lane >> 4, l16 = lane & 15;
  const int wm = (w >> 1) * 32, wn = (w & 1) * 64;
  const int cid = (blockIdx.x & 7) * 64 + (blockIdx.x >> 3);
  const int bn = (cid & 7) * 128, bm = (cid >> 3) * 64;
  f32x4 acc[2][4] = {};

  for (int kt = 0; kt < 1024; kt += 64) {
    __syncthreads();
#pragma unroll
    for (int p = 0; p < 2; p++) {
      int idx = p * 256 + tid;  // As: 512 slots = 64 rows x 8 blocks
      int row = idx >> 3, bq = idx & 7;
      int gb = bq ^ (row & 7);
      GLD16(A + (size_t)(bm + row) * 1024 + kt + gb * 8, As + idx * 8);
    }
#pragma unroll
    for (int p = 0; p < 4; p++) {
      int idx = p * 256 + tid;  // Bs: 1024 slots = 128 rows x 8 blocks
      int row = idx >> 3, bq = idx & 7;
      int gb = bq ^ (row & 7);
      GLD16(Bt + (size_t)(bn + row) * 1024 + kt + gb * 8, Bs + idx * 8);
    }
    __syncthreads();

#pragma unroll
    for (int kk = 0; kk < 2; kk++) {
      bf16x8 af[2], bfr[4];
#pragma unroll
      for (int mi = 0; mi < 2; mi++) {
        int row = wm + mi * 16 + l16;
        int sb = (kk * 4 + quad) ^ (row & 7);
        af[mi] = *(const bf16x8*)(As + row * 64 + sb * 8);
      }
#pragma unroll
      for (int ni = 0; ni < 4; ni++) {
        int row = wn + ni * 16 + l16;
        int sb = (kk * 4 + quad) ^ (row & 7);
        bfr[ni] = *(const bf16x8*)(Bs + row * 64 + sb * 8);
      }
#pragma unroll
      for (int mi = 0; mi < 2; mi++)
#pragma unroll
        for (int ni = 0; ni < 4; ni++)
          acc[mi][ni] =
              __builtin_amdgcn_mfma_f32_16x16x32_bf16(af[mi], bfr[ni], acc[mi][ni], 0, 0, 0);
    }
  }

#pragma unroll
  for (int ni = 0; ni < 4; ni++) {
    int col = bn + wn + ni * 16 + l16;
    float bv = bias[col];
#pragma unroll
    for (int mi = 0; mi < 2; mi++)
#pragma unroll
      for (int r = 0; r < 4; r++) {
        int row = bm + wm + mi * 16 + quad * 4 + r;
        outF[(size_t)row * 1024 + col] = acc[mi][ni][r] + bv;
      }
  }
}

// ---------------- flash attention (round-4 version, verbatim: measured 47.6-48.1us) --
// 4-wave blocks, grid 512 = 2 blocks/CU, dbuf K/V (32KB), one __syncthreads/iter.
// 8 variants (schedules, barriers, occupancy, read-amortization) all landed 47.3-53:
// this decomposition's fixed point. P trick: S^T=K*Q^T leaves lane with
// key=(reg&3)+8*(reg>>2)+4h, qrow=l&31; PV k-order arbitrary -> pf[c] = exp2 of own
// acc regs in order (no cross-lane, no LDS round-trip); V stored key-permuted
// (bits 2<->3, in k_gemm_qkv) so each pf[c]'s V A-fragment is one b128.
__global__ __launch_bounds__(256, 2) void k_flash(
    const bf16* __restrict__ Q, const bf16* __restrict__ K,
    const bf16* __restrict__ V, bf16* __restrict__ O) {
  __shared__ __align__(16) bf16 Kt[2][64 * 64];  // [key][d]
  __shared__ __align__(16) bf16 Vt[2][64 * 64];  // [d][key'] (key-permuted)
  const int tid = threadIdx.x;
  const int lane = tid & 63, w = tid >> 6;
  const int l31 = lane & 31, h = lane >> 5;
  const int x7 = l31 & 7;
  const int cid = ((blockIdx.x & 7) << 6) | (blockIdx.x >> 3);  // bijective XCD chunking
  const int qt = cid & 15, bh = cid >> 4;
  const bf16* qh = Q + (size_t)bh * 2048 * 64;
  const bf16* kh = K + (size_t)bh * 2048 * 64;
  const bf16* vh = V + (size_t)bh * 64 * 2048;
  const int qrow = qt * 128 + w * 32 + l31;

  // Q fragments (B-operand of S^T = K*Q^T): slot(h,j) -> d = 16c + 8h + j
  bf16x8 qf[4];
#pragma unroll
  for (int c4 = 0; c4 < 4; c4++)
    qf[c4] = *(const bf16x8*)(qh + (size_t)qrow * 64 + c4 * 16 + h * 8);

  bf16x8 ones;
#pragma unroll
  for (int j = 0; j < 8; j++) ones[j] = (bf16)1.0f;
  f32x16 z16 = {};  // loop-invariant zero C-operand for the first S-MFMA

  f32x16 o0 = {}, o1 = {};  // O^T acc: d = 32*db + (reg&3)+8*(reg>>2)+4h, col = qrow
  f32x16 lacc = {};         // ones-MFMA row-sum acc (all rows equal per col)

  auto stage = [&](int kt2, int buf) {
#pragma unroll
    for (int pp = 0; pp < 2; pp++) {
      int idx = pp * 256 + tid;
      int row = idx >> 3, bq = idx & 7, gb = bq ^ (row & 7);
      GLD16(kh + (size_t)(kt2 * 64 + row) * 64 + gb * 8, &Kt[buf][idx * 8]);
      GLD16(vh + (size_t)row * 2048 + kt2 * 64 + gb * 8, &Vt[buf][idx * 8]);
    }
  };

  stage(0, 0);

  for (int kt2 = 0; kt2 < 32; kt2++) {
    const int p = kt2 & 1;
    __syncthreads();               // publishes buf[p]; prior readers of buf[p^1] done
    if (kt2 < 31) stage(kt2 + 1, p ^ 1);
    const bf16* Kb = &Kt[p][0];
    const bf16* Vb = &Vt[p][0];

    // S^T = K*Q^T, two 32-key blocks
    f32x16 a0, a1;
    {
      const bf16* k0 = Kb + l31 * 64;
      const bf16* k1 = k0 + 32 * 64;
      __builtin_amdgcn_s_setprio(1);
#pragma unroll
      for (int c4 = 0; c4 < 4; c4++) {
        int off = ((2 * c4 + h) ^ x7) << 3;
        bf16x8 kf0 = *(const bf16x8*)(k0 + off);
        bf16x8 kf1 = *(const bf16x8*)(k1 + off);
        a0 = __builtin_amdgcn_mfma_f32_32x32x16_bf16(kf0, qf[c4], c4 ? a0 : z16, 0, 0, 0);
        a1 = __builtin_amdgcn_mfma_f32_32x32x16_bf16(kf1, qf[c4], c4 ? a1 : z16, 0, 0, 0);
      }
      __builtin_amdgcn_s_setprio(0);
    }

    const bf16* v0 = Vb + l31 * 64;
    const bf16* v1 = v0 + 32 * 64;

    // half 1: P(c=0,1) from a0, then PV + lsum MFMAs
    {
      bf16x8 pf0, pf1;
#pragma unroll
      for (int j = 0; j < 8; j++) {
        pf0[j] = (bf16)__builtin_amdgcn_exp2f(a0[j]);
        pf1[j] = (bf16)__builtin_amdgcn_exp2f(a0[8 + j]);
      }
      int e0 = ((0 + h) ^ x7) << 3, e1 = ((2 + h) ^ x7) << 3;
      bf16x8 vf00 = *(const bf16x8*)(v0 + e0);
      bf16x8 vf10 = *(const bf16x8*)(v1 + e0);
      bf16x8 vf01 = *(const bf16x8*)(v0 + e1);
      bf16x8 vf11 = *(const bf16x8*)(v1 + e1);
      __builtin_amdgcn_s_setprio(1);
      lacc = __builtin_amdgcn_mfma_f32_32x32x16_bf16(ones, pf0, lacc, 0, 0, 0);
      o0 = __builtin_amdgcn_mfma_f32_32x32x16_bf16(vf00, pf0, o0, 0, 0, 0);
      o1 = __builtin_amdgcn_mfma_f32_32x32x16_bf16(vf10, pf0, o1, 0, 0, 0);
      lacc = __builtin_amdgcn_mfma_f32_32x32x16_bf16(ones, pf1, lacc, 0, 0, 0);
      o0 = __builtin_amdgcn_mfma_f32_32x32x16_bf16(vf01, pf1, o0, 0, 0, 0);
      o1 = __builtin_amdgcn_mfma_f32_32x32x16_bf16(vf11, pf1, o1, 0, 0, 0);
      __builtin_amdgcn_s_setprio(0);
    }

    // half 2: P(c=2,3) from a1, then PV + lsum MFMAs
    {
      bf16x8 pf2, pf3;
#pragma unroll
      for (int j = 0; j < 8; j++) {
        pf2[j] = (bf16)__builtin_amdgcn_exp2f(a1[j]);
        pf3[j] = (bf16)__builtin_amdgcn_exp2f(a1[8 + j]);
      }
      int e2 = ((4 + h) ^ x7) << 3, e3 = ((6 + h) ^ x7) << 3;
      bf16x8 vf02 = *(const bf16x8*)(v0 + e2);
      bf16x8 vf12 = *(const bf16x8*)(v1 + e2);
      bf16x8 vf03 = *(const bf16x8*)(v0 + e3);
      bf16x8 vf13 = *(const bf16x8*)(v1 + e3);
      __builtin_amdgcn_s_setprio(1);
      lacc = __builtin_amdgcn_mfma_f32_32x32x16_bf16(ones, pf2, lacc, 0, 0, 0);
      o0 = __builtin_amdgcn_mfma_f32_32x32x16_bf16(vf02, pf2, o0, 0, 0, 0);
      o1 = __builtin_amdgcn_mfma_f32_32x32x16_bf16(vf12, pf2, o1, 0, 0, 0);
      lacc = __builtin_amdgcn_mfma_f32_32x32x16_bf16(ones, pf3, lacc, 0, 0, 0);
      o0 = __builtin_amdgcn_mfma_f32_32x32x16_bf16(vf03, pf3, o0, 0, 0, 0);
      o1 = __builtin_amdgcn_mfma_f32_32x32x16_bf16(vf13, pf3, o1, 0, 0, 0);
      __builtin_amdgcn_s_setprio(0);
    }
  }

  // epilogue: lacc rows all hold the full key-sum for col = qrow (both halves)
  float inv = 1.0f / lacc[0];
  const int bb = bh >> 4, hh = bh & 15;
  bf16* orow = O + ((size_t)bb * 2048 + qrow) * 1024 + hh * 64;
#pragma unroll
  for (int g = 0; g < 4; g++) {
    bf16x4 ov0, ov1;
#pragma unroll
    for (int r = 0; r < 4; r++) {
      ov0[r] = (bf16)(o0[4 * g + r] * inv);
      ov1[r] = (bf16)(o1[4 * g + r] * inv);
    }
    *(bf16x4*)(orow + 8 * g + 4 * h) = ov0;        // d = 8g + 4h + r
    *(bf16x4*)(orow + 32 + 8 * g + 4 * h) = ov1;   // d = 32 + 8g + 4h + r
  }
}

// ---------------- launch ----------------

extern "C" void kernel_launch(void* const* d_in, const int* in_sizes, int n_in,
                              void* d_out, int out_size, void* d_ws, size_t ws_size,
                              hipStream_t stream) {
  (void)in_sizes; (void)n_in; (void)out_size; (void)ws_size;
  const float* x    = (const float*)d_in[0];
  const float* Wqkv = (const float*)d_in[1];
  const float* bqkv = (const float*)d_in[2];
  const float* Wout = (const float*)d_in[3];
  const float* bout = (const float*)d_in[4];
  float* out = (float*)d_out;

  char* ws = (char*)d_ws;
  size_t off = 0;
  auto take = [&](size_t bytes) {
    char* p = ws + off;
    off += (bytes + 255) & ~(size_t)255;
    return p;
  };
  bf16* xb   = (bf16*)take((size_t)4096 * 1024 * 2);
  bf16* wqT  = (bf16*)take((size_t)3072 * 1024 * 2);
  bf16* woT  = (bf16*)take((size_t)1024 * 1024 * 2);
  bf16* qbuf = (bf16*)take((size_t)32 * 2048 * 64 * 2);
  bf16* kbuf = (bf16*)take((size_t)32 * 2048 * 64 * 2);
  bf16* vbuf = (bf16*)take((size_t)32 * 2048 * 64 * 2);
  bf16* aout = (bf16*)take((size_t)4096 * 1024 * 2);

  k_prep<<<6144, 256, 0, stream>>>(x, Wqkv, Wout, xb, wqT, woT);
  k_gemm_qkv<<<dim3(24, 32), 256, 0, stream>>>(xb, wqT, bqkv, qbuf, kbuf, vbuf);
  k_flash<<<dim3(512), 256, 0, stream>>>(qbuf, kbuf, vbuf, aout);
  k_gemm_out<<<dim3(512), 256, 0, stream>>>(aout, woT, bout, out);
}